// Round 1
// baseline (200.162 us; speedup 1.0000x reference)
//
#include <hip/hip_runtime.h>

#define M_DIM 512
#define N_DIM 4096
#define K_DIM 4096
#define SPLITK 4
#define KC (K_DIM / SPLITK)

typedef __attribute__((ext_vector_type(8))) __bf16 bf16x8;
typedef __attribute__((ext_vector_type(4))) float f32x4;

// ---------------------------------------------------------------- amax ------
__global__ void amax_kernel(const float4* __restrict__ v, int n4,
                            unsigned int* __restrict__ slot) {
    float m = 0.0f;
    for (int i = blockIdx.x * blockDim.x + threadIdx.x; i < n4;
         i += gridDim.x * blockDim.x) {
        float4 a = v[i];
        m = fmaxf(m, fmaxf(fmaxf(fabsf(a.x), fabsf(a.y)),
                           fmaxf(fabsf(a.z), fabsf(a.w))));
    }
    // wave (64-lane) reduce
    for (int off = 32; off > 0; off >>= 1)
        m = fmaxf(m, __shfl_down(m, off, 64));
    __shared__ float sm[4];
    if ((threadIdx.x & 63) == 0) sm[threadIdx.x >> 6] = m;
    __syncthreads();
    if (threadIdx.x == 0) {
        m = fmaxf(fmaxf(sm[0], sm[1]), fmaxf(sm[2], sm[3]));
        atomicMax(slot, __float_as_uint(m));  // valid: all values >= 0
    }
}

// ------------------------------------------------------------- quantize -----
// Produce bf16 bit patterns of the e2m1 codebook VALUES (sign * magnitude),
// in codebook units (scale undone in GEMM epilogue). Midpoint ties -> smaller
// magnitude (matches jnp.argmin first-occurrence).
__device__ __forceinline__ unsigned short quant1(float x, float s) {
    float a = fabsf(x) * s;  // == |x*s|, s>0
    unsigned short b;
    if      (a <= 0.25f) b = 0x0000;  // 0.0
    else if (a <= 0.75f) b = 0x3F00;  // 0.5
    else if (a <= 1.25f) b = 0x3F80;  // 1.0
    else if (a <= 1.75f) b = 0x3FC0;  // 1.5
    else if (a <= 2.5f)  b = 0x4000;  // 2.0
    else if (a <= 3.5f)  b = 0x4040;  // 3.0
    else if (a <= 5.0f)  b = 0x4080;  // 4.0
    else                 b = 0x40C0;  // 6.0 (also handles clip > 6)
    return (unsigned short)(b | ((__float_as_uint(x) >> 16) & 0x8000u));
}

__global__ void quant_kernel(const float4* __restrict__ in,
                             ushort4* __restrict__ out, int n4,
                             const float* __restrict__ amax_p) {
    float amax = fmaxf(*amax_p, 1e-12f);
    float s = 6.0f / amax;  // same fp32 op order as reference
    for (int i = blockIdx.x * blockDim.x + threadIdx.x; i < n4;
         i += gridDim.x * blockDim.x) {
        float4 a = in[i];
        ushort4 q;
        q.x = quant1(a.x, s);
        q.y = quant1(a.y, s);
        q.z = quant1(a.z, s);
        q.w = quant1(a.w, s);
        out[i] = q;
    }
}

// ----------------------------------------------------------------- GEMM -----
__device__ __forceinline__ void async_copy16(const void* g, void* l) {
    __builtin_amdgcn_global_load_lds(
        (const __attribute__((address_space(1))) unsigned int*)g,
        (__attribute__((address_space(3))) unsigned int*)l, 16, 0, 0);
}

// C[m,n] = sum_k A[m,k] * B[n,k]  (both row-major, dot along contiguous K)
// 128x128 block tile, BK=32, 4 waves each 64x64 (4x4 of 16x16x32 MFMA),
// split-K=4 with fp32 atomicAdd epilogue scaled by inv_x*inv_w.
__global__ __launch_bounds__(256, 2) void gemm_kernel(
    const __bf16* __restrict__ A, const __bf16* __restrict__ B,
    float* __restrict__ C, const float* __restrict__ amax) {
    __shared__ __align__(16) __bf16 As[128 * 32];
    __shared__ __align__(16) __bf16 Bs[128 * 32];

    const int bid  = blockIdx.x;
    const int sk   = bid & (SPLITK - 1);
    const int t2   = bid >> 2;
    const int bm   = (t2 & 3) * 128;   // M/128 = 4
    const int bn   = (t2 >> 2) * 128;  // N/128 = 32
    const int tid  = threadIdx.x;
    const int lane = tid & 63;
    const int wave = tid >> 6;
    const int wm   = (wave >> 1) * 64;
    const int wn   = (wave & 1) * 64;
    const int t15  = lane & 15;
    const int quad = lane >> 4;

    float ax = fmaxf(amax[0], 1e-12f);
    float aw = fmaxf(amax[1], 1e-12f);
    float cs = (1.0f / (6.0f / ax)) * (1.0f / (6.0f / aw));  // inv_x * inv_w

    // staging: chunk c = tid + j*256 -> tile row c>>2, col (c&3)*8 elements;
    // LDS byte = c*16 = wave-uniform base + lane*16 (global_load_lds rule)
    const __bf16* ag = A + (size_t)(bm + (tid >> 2)) * K_DIM + sk * KC + (tid & 3) * 8;
    const __bf16* bg = B + (size_t)(bn + (tid >> 2)) * K_DIM + sk * KC + (tid & 3) * 8;
    __bf16* asl = As + wave * 512;  // bytes: wave*1024
    __bf16* bsl = Bs + wave * 512;

    f32x4 acc[4][4] = {};

    for (int k = 0; k < KC; k += 32) {
        async_copy16(ag + k, asl);
        async_copy16(ag + k + (size_t)64 * K_DIM, asl + 2048);
        async_copy16(bg + k, bsl);
        async_copy16(bg + k + (size_t)64 * K_DIM, bsl + 2048);
        __syncthreads();  // compiler drains vmcnt before s_barrier

        bf16x8 af[4], bf[4];
#pragma unroll
        for (int i = 0; i < 4; i++)
            af[i] = *(const bf16x8*)(As + (wm + i * 16 + t15) * 32 + quad * 8);
#pragma unroll
        for (int i = 0; i < 4; i++)
            bf[i] = *(const bf16x8*)(Bs + (wn + i * 16 + t15) * 32 + quad * 8);
#pragma unroll
        for (int i = 0; i < 4; i++)
#pragma unroll
            for (int j = 0; j < 4; j++)
                acc[i][j] = __builtin_amdgcn_mfma_f32_16x16x32_bf16(
                    af[i], bf[j], acc[i][j], 0, 0, 0);
        __syncthreads();
    }

    // C/D layout: col = lane&15 (n), row = quad*4 + reg (m)
#pragma unroll
    for (int i = 0; i < 4; i++)
#pragma unroll
        for (int j = 0; j < 4; j++) {
            int m0 = bm + wm + i * 16 + quad * 4;
            int n0 = bn + wn + j * 16 + t15;
#pragma unroll
            for (int r = 0; r < 4; r++)
                atomicAdd(&C[(size_t)(m0 + r) * N_DIM + n0], acc[i][j][r] * cs);
        }
}

// ---------------------------------------------------------------- launch ----
extern "C" void kernel_launch(void* const* d_in, const int* in_sizes, int n_in,
                              void* d_out, int out_size, void* d_ws, size_t ws_size,
                              hipStream_t stream) {
    const float* x = (const float*)d_in[0];   // [512, 4096]
    const float* w = (const float*)d_in[1];   // [4096, 4096]
    float* out = (float*)d_out;               // [512, 4096]

    // ws layout: [0..16B) amax slots (x,w), then x_q bf16 (4MB), w_q bf16 (32MB)
    float* amax = (float*)d_ws;
    __bf16* xq = (__bf16*)((char*)d_ws + 256);
    __bf16* wq = xq + (size_t)M_DIM * K_DIM;

    hipMemsetAsync(d_ws, 0, 16, stream);                                  // amax = 0
    hipMemsetAsync(d_out, 0, (size_t)M_DIM * N_DIM * sizeof(float), stream);  // split-K acc

    const int nx4 = M_DIM * K_DIM / 4;   // 524288
    const int nw4 = N_DIM * K_DIM / 4;   // 4194304

    amax_kernel<<<1024, 256, 0, stream>>>((const float4*)x, nx4, (unsigned int*)&amax[0]);
    amax_kernel<<<2048, 256, 0, stream>>>((const float4*)w, nw4, (unsigned int*)&amax[1]);
    quant_kernel<<<2048, 256, 0, stream>>>((const float4*)x, (ushort4*)xq, nx4, &amax[0]);
    quant_kernel<<<4096, 256, 0, stream>>>((const float4*)w, (ushort4*)wq, nw4, &amax[1]);

    gemm_kernel<<<(M_DIM / 128) * (N_DIM / 128) * SPLITK, 256, 0, stream>>>(
        xq, wq, out, amax);
}

// Round 2
// 180.411 us; speedup vs baseline: 1.1095x; 1.1095x over previous
//
#include <hip/hip_runtime.h>

#define M_DIM 512
#define N_DIM 4096
#define K_DIM 4096
#define SPLITK 8
#define KC (K_DIM / SPLITK)   // 512

typedef __attribute__((ext_vector_type(4))) float f32x4;

// ---- ws layout ----
// float slots: [0,256) part_x, [256,1280) part_w, [1280,1282) amax_final{x,w}
// bytes: xq fp8 at 8192 (2 MB), wq fp8 at 8192+2MB (16 MB)
#define PART_X_OFF 0
#define PART_X_N   256
#define PART_W_OFF 256
#define PART_W_N   1024
#define AMAX_OFF   1280
#define XQ_BYTE_OFF 8192
#define WQ_BYTE_OFF (8192 + M_DIM * K_DIM)

// ---------------------------------------------------------------- amax ------
__global__ __launch_bounds__(256) void amax_kernel(
    const float4* __restrict__ x4, const float4* __restrict__ w4,
    float* __restrict__ ws_f) {
    const int b = blockIdx.x;
    float m = 0.0f;
    if (b < PART_X_N) {  // x: 256 blocks
        const int n4 = M_DIM * K_DIM / 4, stride = PART_X_N * 256;
        for (int i = b * 256 + threadIdx.x; i < n4; i += stride) {
            float4 a = x4[i];
            m = fmaxf(m, fmaxf(fmaxf(fabsf(a.x), fabsf(a.y)),
                               fmaxf(fabsf(a.z), fabsf(a.w))));
        }
    } else {             // w: 1024 blocks
        const int n4 = N_DIM * K_DIM / 4, stride = PART_W_N * 256;
        for (int i = (b - PART_X_N) * 256 + threadIdx.x; i < n4; i += stride) {
            float4 a = w4[i];
            m = fmaxf(m, fmaxf(fmaxf(fabsf(a.x), fabsf(a.y)),
                               fmaxf(fabsf(a.z), fabsf(a.w))));
        }
    }
    for (int off = 32; off > 0; off >>= 1)
        m = fmaxf(m, __shfl_down(m, off, 64));
    __shared__ float sm[4];
    if ((threadIdx.x & 63) == 0) sm[threadIdx.x >> 6] = m;
    __syncthreads();
    if (threadIdx.x == 0) {
        m = fmaxf(fmaxf(sm[0], sm[1]), fmaxf(sm[2], sm[3]));
        ws_f[(b < PART_X_N) ? (PART_X_OFF + b) : (PART_W_OFF + b - PART_X_N)] = m;
    }
}

// ------------------------------------------------------------- quantize -----
// e2m1 codebook values as OCP e4m3fn bytes (exact): 0,0.5,1,1.5,2,3,4,6.
// Midpoint ties -> smaller magnitude (matches jnp.argmin first-occurrence).
__device__ __forceinline__ unsigned int q1(float x, float s) {
    float a = fabsf(x) * s;
    unsigned int b;
    if      (a <= 0.25f) b = 0x00u;  // 0.0
    else if (a <= 0.75f) b = 0x30u;  // 0.5
    else if (a <= 1.25f) b = 0x38u;  // 1.0
    else if (a <= 1.75f) b = 0x3Cu;  // 1.5
    else if (a <= 2.5f)  b = 0x40u;  // 2.0
    else if (a <= 3.5f)  b = 0x44u;  // 3.0
    else if (a <= 5.0f)  b = 0x48u;  // 4.0
    else                 b = 0x4Cu;  // 6.0 (also handles clip)
    return b | ((__float_as_uint(x) >> 24) & 0x80u);
}
__device__ __forceinline__ unsigned int qpack4(float4 v, float s) {
    return q1(v.x, s) | (q1(v.y, s) << 8) | (q1(v.z, s) << 16) | (q1(v.w, s) << 24);
}

__global__ __launch_bounds__(256) void quant_kernel(
    const float4* __restrict__ x4, const float4* __restrict__ w4,
    float* __restrict__ ws_f, unsigned char* __restrict__ ws_b) {
    const int b = blockIdx.x, t = threadIdx.x;
    const bool is_x = b < 512;
    float m = 0.0f;
    if (is_x) {
        m = ws_f[PART_X_OFF + t];  // 256 threads, 256 slots
    } else {
        for (int i = t; i < PART_W_N; i += 256)
            m = fmaxf(m, ws_f[PART_W_OFF + i]);
    }
    for (int off = 32; off > 0; off >>= 1)
        m = fmaxf(m, __shfl_down(m, off, 64));
    __shared__ float sm[4];
    if ((t & 63) == 0) sm[t >> 6] = m;
    __syncthreads();
    m = fmaxf(fmaxf(sm[0], sm[1]), fmaxf(sm[2], sm[3]));
    float amax = fmaxf(m, 1e-12f);
    float s = 6.0f / amax;
    if (t == 0 && b == 0)   ws_f[AMAX_OFF + 0] = amax;
    if (t == 0 && b == 512) ws_f[AMAX_OFF + 1] = amax;

    const float4* src = is_x ? x4 : w4;
    unsigned char* dstb = ws_b + (is_x ? XQ_BYTE_OFF : WQ_BYTE_OFF);
    const int idx16 = (is_x ? b : b - 512) * 256 + t;  // 16-float chunk index
    const float4* p = src + (size_t)idx16 * 4;
    uint4 o;
    o.x = qpack4(p[0], s);
    o.y = qpack4(p[1], s);
    o.z = qpack4(p[2], s);
    o.w = qpack4(p[3], s);
    ((uint4*)dstb)[idx16] = o;
}

// ----------------------------------------------------------------- GEMM -----
__device__ __forceinline__ void async_copy16(const void* g, void* l) {
    __builtin_amdgcn_global_load_lds(
        (const __attribute__((address_space(1))) unsigned int*)g,
        (__attribute__((address_space(3))) unsigned int*)l, 16, 0, 0);
}

// C[m,n] = sum_k A[m,k]*B[n,k], fp8 operands (codebook units), fp32 atomic
// splitk epilogue. 128x128 tile, BK=64, 4 waves of 64x64 (4x4x2 16x16x32).
// LDS placement XOR-swizzled via global-chunk selection: chunk for physical
// slot (row, col) holds global col^((row>>1)&3) -> frag ds_read_b64 is
// 2-way-per-half-wave (free).
__global__ __launch_bounds__(256, 4) void gemm_kernel(
    const unsigned char* __restrict__ A, const unsigned char* __restrict__ B,
    float* __restrict__ C, const float* __restrict__ amax2) {
    __shared__ __align__(16) unsigned char As[128 * 64];
    __shared__ __align__(16) unsigned char Bs[128 * 64];

    const int bid  = blockIdx.x;
    const int sk   = bid & (SPLITK - 1);
    const int t2   = bid >> 3;
    const int bm   = (t2 & 3) * 128;   // M/128 = 4
    const int bn   = (t2 >> 2) * 128;  // N/128 = 32
    const int tid  = threadIdx.x;
    const int lane = tid & 63;
    const int wave = tid >> 6;
    const int wm   = (wave >> 1) * 64;
    const int wn   = (wave & 1) * 64;
    const int t15  = lane & 15;
    const int quad = lane >> 4;

    const float cs = (1.0f / (6.0f / fmaxf(amax2[0], 1e-12f))) *
                     (1.0f / (6.0f / fmaxf(amax2[1], 1e-12f)));

    // staging: slot c = tid + j*256 -> LDS byte c*16; physical (row=c>>2,
    // col=c&3) loads global col (c&3)^((row>>1)&3)
    const int r0 = tid >> 2, r1 = r0 + 64;
    const int c0 = (tid & 3) ^ ((r0 >> 1) & 3);
    const int c1 = (tid & 3) ^ ((r1 >> 1) & 3);
    const unsigned char* a0 = A + (size_t)(bm + r0) * K_DIM + sk * KC + c0 * 16;
    const unsigned char* a1 = A + (size_t)(bm + r1) * K_DIM + sk * KC + c1 * 16;
    const unsigned char* b0 = B + (size_t)(bn + r0) * K_DIM + sk * KC + c0 * 16;
    const unsigned char* b1 = B + (size_t)(bn + r1) * K_DIM + sk * KC + c1 * 16;
    unsigned char* asl0 = As + wave * 1024;
    unsigned char* asl1 = As + 4096 + wave * 1024;
    unsigned char* bsl0 = Bs + wave * 1024;
    unsigned char* bsl1 = Bs + 4096 + wave * 1024;

    f32x4 acc[4][4] = {};

    for (int k = 0; k < KC; k += 64) {
        async_copy16(a0 + k, asl0);
        async_copy16(a1 + k, asl1);
        async_copy16(b0 + k, bsl0);
        async_copy16(b1 + k, bsl1);
        __syncthreads();

        long af[2][4], bf[2][4];
#pragma unroll
        for (int h = 0; h < 2; h++)
#pragma unroll
            for (int i = 0; i < 4; i++) {
                const int lc = (quad >> 1) + h * 2;      // logical 16B col
                const int mrow = wm + i * 16 + t15;
                const int nrow = wn + i * 16 + t15;
                af[h][i] = *(const long*)(As + mrow * 64 +
                                          (lc ^ ((mrow >> 1) & 3)) * 16 +
                                          (quad & 1) * 8);
                bf[h][i] = *(const long*)(Bs + nrow * 64 +
                                          (lc ^ ((nrow >> 1) & 3)) * 16 +
                                          (quad & 1) * 8);
            }
#pragma unroll
        for (int h = 0; h < 2; h++)
#pragma unroll
            for (int i = 0; i < 4; i++)
#pragma unroll
                for (int j = 0; j < 4; j++)
                    acc[i][j] = __builtin_amdgcn_mfma_f32_16x16x32_fp8_fp8(
                        af[h][i], bf[h][j], acc[i][j], 0, 0, 0);
        __syncthreads();
    }

    // C/D layout: col = lane&15 (n), row = quad*4 + reg (m)
#pragma unroll
    for (int i = 0; i < 4; i++)
#pragma unroll
        for (int j = 0; j < 4; j++) {
            const int m0 = bm + wm + i * 16 + quad * 4;
            const int n0 = bn + wn + j * 16 + t15;
#pragma unroll
            for (int r = 0; r < 4; r++)
                atomicAdd(&C[(size_t)(m0 + r) * N_DIM + n0], acc[i][j][r] * cs);
        }
}

// ---------------------------------------------------------------- launch ----
extern "C" void kernel_launch(void* const* d_in, const int* in_sizes, int n_in,
                              void* d_out, int out_size, void* d_ws, size_t ws_size,
                              hipStream_t stream) {
    const float* x = (const float*)d_in[0];   // [512, 4096]
    const float* w = (const float*)d_in[1];   // [4096, 4096]
    float* out = (float*)d_out;               // [512, 4096]

    float* ws_f = (float*)d_ws;
    unsigned char* ws_b = (unsigned char*)d_ws;
    const unsigned char* xq = ws_b + XQ_BYTE_OFF;
    const unsigned char* wq = ws_b + WQ_BYTE_OFF;

    hipMemsetAsync(d_out, 0, (size_t)M_DIM * N_DIM * sizeof(float), stream);

    amax_kernel<<<PART_X_N + PART_W_N, 256, 0, stream>>>(
        (const float4*)x, (const float4*)w, ws_f);
    quant_kernel<<<512 + 4096, 256, 0, stream>>>(
        (const float4*)x, (const float4*)w, ws_f, ws_b);
    gemm_kernel<<<(M_DIM / 128) * (N_DIM / 128) * SPLITK, 256, 0, stream>>>(
        xq, wq, out, ws_f + AMAX_OFF);
}